// Round 4
// baseline (449.510 us; speedup 1.0000x reference)
//
#include <hip/hip_runtime.h>
#include <hip/hip_cooperative_groups.h>
#include <cstdint>
#include <cstddef>

namespace cg = cooperative_groups;

// FusedBitLinear, single cooperative kernel:
//  Phase A: alpha partials over |W| rows  +  RMSNorm/gamma/int8-quant of x rows
//  grid.sync()
//  Phase B: alpha = max(mean|W|,1e-10) recomputed per-block (bit-identical
//           reduction order -> deterministic), ternary-quant W rows
//  grid.sync()
//  Phase C: int8 MFMA GEMM, 128x128 tile, BK=128, swizzled global_load_lds
//           staging (round-3 structure, measured 0 bank conflicts), epilogue
//           scales by alpha*gamma[m]/127 (alpha held in register from B).
//
// M=4096 tokens, K=4096, N=4096. fp32 in/out.
//
// ws layout:
//   [0, 16M)            xq   int8 [4096][4096]
//   [16M, 32M)          wq   int8 [4096][4096]
//   [32M, +16KB)        gamma float[4096]
//   [+16KB, +32KB)      alpha partials float[4096]

#define KD 4096
#define MD 4096
#define ND 4096
#define NTILE 1024  // (4096/128)^2

typedef int i32x4 __attribute__((ext_vector_type(4)));

__device__ __forceinline__ void gl2lds16(const signed char* g, signed char* l) {
  __builtin_amdgcn_global_load_lds(
      (const __attribute__((address_space(1))) void*)g,
      (__attribute__((address_space(3))) void*)l, 16, 0, 0);
}

__device__ __forceinline__ float wave_sum(float v) {
#pragma unroll
  for (int off = 32; off; off >>= 1) v += __shfl_down(v, off, 64);
  return v;
}
__device__ __forceinline__ float wave_max(float v) {
#pragma unroll
  for (int off = 32; off; off >>= 1) v = fmaxf(v, __shfl_down(v, off, 64));
  return v;
}

__global__ __launch_bounds__(256, 4) void k_fused(
    const float* __restrict__ x, const float* __restrict__ w,
    const float* __restrict__ nw, signed char* __restrict__ xq,
    signed char* __restrict__ wq, float* __restrict__ gamma,
    float* __restrict__ part, float* __restrict__ out) {
  __shared__ __align__(16) signed char As[128 * 128];
  __shared__ __align__(16) signed char Bs[128 * 128];
  __shared__ float red[4];
  __shared__ float red2[4];

  const int tid = threadIdx.x;
  const int bid = blockIdx.x;
  const int nblk = gridDim.x;
  cg::grid_group grid = cg::this_grid();

  // ================= Phase A =================
  // |W| row partial sums
  for (int row = bid; row < 4096; row += nblk) {
    const float4* w4 = (const float4*)(w + (size_t)row * 4096);
    float s = 0.f;
#pragma unroll
    for (int j = 0; j < 4; ++j) {
      float4 v = w4[j * 256 + tid];
      s += fabsf(v.x) + fabsf(v.y) + fabsf(v.z) + fabsf(v.w);
    }
    s = wave_sum(s);
    __syncthreads();
    if ((tid & 63) == 0) red[tid >> 6] = s;
    __syncthreads();
    if (tid == 0) part[row] = (red[0] + red[1]) + (red[2] + red[3]);
  }

  // RMSNorm + gamma + int8 x-quant
  for (int row = bid; row < 4096; row += nblk) {
    const float4* x4 = (const float4*)(x + (size_t)row * 4096);
    const float4* n4 = (const float4*)nw;
    float4 xv[4], nv[4];
    float ss = 0.f;
#pragma unroll
    for (int i = 0; i < 4; ++i) {
      xv[i] = x4[i * 256 + tid];
      nv[i] = n4[i * 256 + tid];
      ss += xv[i].x * xv[i].x + xv[i].y * xv[i].y + xv[i].z * xv[i].z +
            xv[i].w * xv[i].w;
    }
    ss = wave_sum(ss);
    __syncthreads();
    if ((tid & 63) == 0) red[tid >> 6] = ss;
    __syncthreads();
    const float tot = (red[0] + red[1]) + (red[2] + red[3]);
    const float rms = sqrtf(tot * (1.0f / 4096.0f) + 1e-6f);

    float4 xn[4];
    float mx = 0.f;
#pragma unroll
    for (int i = 0; i < 4; ++i) {
      xn[i].x = xv[i].x / rms * nv[i].x;
      xn[i].y = xv[i].y / rms * nv[i].y;
      xn[i].z = xv[i].z / rms * nv[i].z;
      xn[i].w = xv[i].w / rms * nv[i].w;
      mx = fmaxf(mx, fmaxf(fmaxf(fabsf(xn[i].x), fabsf(xn[i].y)),
                           fmaxf(fabsf(xn[i].z), fabsf(xn[i].w))));
    }
    mx = wave_max(mx);
    __syncthreads();
    if ((tid & 63) == 0) red2[tid >> 6] = mx;
    __syncthreads();
    const float g = fmaxf(
        fmaxf(fmaxf(red2[0], red2[1]), fmaxf(red2[2], red2[3])), 1e-10f);
    if (tid == 0) gamma[row] = g;

    uint32_t* xqi = (uint32_t*)(xq + (size_t)row * 4096);
#pragma unroll
    for (int i = 0; i < 4; ++i) {
      const int f = i * 256 + tid;
      int q0 = (int)fminf(fmaxf(rintf(xn[i].x * 127.0f / g), -128.f), 127.f);
      int q1 = (int)fminf(fmaxf(rintf(xn[i].y * 127.0f / g), -128.f), 127.f);
      int q2 = (int)fminf(fmaxf(rintf(xn[i].z * 127.0f / g), -128.f), 127.f);
      int q3 = (int)fminf(fmaxf(rintf(xn[i].w * 127.0f / g), -128.f), 127.f);
      xqi[f] = (uint32_t)(q0 & 255) | ((uint32_t)(q1 & 255) << 8) |
               ((uint32_t)(q2 & 255) << 16) | ((uint32_t)(q3 & 255) << 24);
    }
  }

  grid.sync();

  // ================= Phase B =================
  // alpha: identical reduction order in every block -> deterministic
  float s = 0.f;
#pragma unroll
  for (int i = 0; i < 16; ++i) s += part[i * 256 + tid];
  s = wave_sum(s);
  __syncthreads();
  if ((tid & 63) == 0) red[tid >> 6] = s;
  __syncthreads();
  const float alpha =
      fmaxf(((red[0] + red[1]) + (red[2] + red[3])) * (1.0f / 16777216.0f),
            1e-10f);

  for (int row = bid; row < 4096; row += nblk) {
    const float4* w4 = (const float4*)(w + (size_t)row * 4096);
    uint32_t* wqi = (uint32_t*)(wq + (size_t)row * 4096);
#pragma unroll
    for (int i = 0; i < 4; ++i) {
      const int f = i * 256 + tid;
      float4 v = w4[f];
      int q0 = (int)fminf(fmaxf(rintf(v.x / alpha), -1.f), 1.f);
      int q1 = (int)fminf(fmaxf(rintf(v.y / alpha), -1.f), 1.f);
      int q2 = (int)fminf(fmaxf(rintf(v.z / alpha), -1.f), 1.f);
      int q3 = (int)fminf(fmaxf(rintf(v.w / alpha), -1.f), 1.f);
      wqi[f] = (uint32_t)(q0 & 255) | ((uint32_t)(q1 & 255) << 8) |
               ((uint32_t)(q2 & 255) << 16) | ((uint32_t)(q3 & 255) << 24);
    }
  }

  grid.sync();

  // ================= Phase C: GEMM =================
  const int lane = tid & 63;
  const int wave = tid >> 6;
  const int wm = (wave >> 1) * 64;
  const int wn = (wave & 1) * 64;
  const int quad = lane >> 4;
  const int l16 = lane & 15;
  const int lr = lane >> 3;
  const int sc = (lane & 7) ^ lr;
  const int swz = l16 & 7;

  for (int tile = bid; tile < NTILE; tile += nblk) {
    const int bm = (tile >> 5) * 128;
    const int bn = (tile & 31) * 128;
    const signed char* Ag = xq + (size_t)bm * KD;
    const signed char* Bg = wq + (size_t)bn * KD;

    const signed char* agp[4];
    const signed char* bgp[4];
    signed char* la[4];
    signed char* lb[4];
#pragma unroll
    for (int i = 0; i < 4; ++i) {
      const int R = i * 32 + wave * 8 + lr;
      agp[i] = Ag + (size_t)R * KD + sc * 16;
      bgp[i] = Bg + (size_t)R * KD + sc * 16;
      la[i] = &As[(i * 32 + wave * 8) * 128];
      lb[i] = &Bs[(i * 32 + wave * 8) * 128];
    }

    i32x4 acc[4][4];
#pragma unroll
    for (int i = 0; i < 4; ++i)
#pragma unroll
      for (int j = 0; j < 4; ++j) acc[i][j] = (i32x4){0, 0, 0, 0};

    for (int k0 = 0; k0 < KD; k0 += 128) {
      __syncthreads();
#pragma unroll
      for (int i = 0; i < 4; ++i) gl2lds16(agp[i] + k0, la[i]);
#pragma unroll
      for (int i = 0; i < 4; ++i) gl2lds16(bgp[i] + k0, lb[i]);
      __syncthreads();

#pragma unroll
      for (int ks = 0; ks < 2; ++ks) {
        const int pos = ((ks * 4 + quad) ^ swz) * 16;
        i32x4 af[4], bf[4];
#pragma unroll
        for (int mi = 0; mi < 4; ++mi)
          af[mi] = *(const i32x4*)&As[(wm + mi * 16 + l16) * 128 + pos];
#pragma unroll
        for (int ni = 0; ni < 4; ++ni)
          bf[ni] = *(const i32x4*)&Bs[(wn + ni * 16 + l16) * 128 + pos];
#pragma unroll
        for (int mi = 0; mi < 4; ++mi)
#pragma unroll
          for (int ni = 0; ni < 4; ++ni)
            acc[mi][ni] = __builtin_amdgcn_mfma_i32_16x16x64_i8(
                af[mi], bf[ni], acc[mi][ni], 0, 0, 0);
      }
    }

#pragma unroll
    for (int mi = 0; mi < 4; ++mi) {
#pragma unroll
      for (int r = 0; r < 4; ++r) {
        const int m = bm + wm + mi * 16 + quad * 4 + r;
        const float sc2 = (alpha * gamma[m]) / 127.0f;
#pragma unroll
        for (int ni = 0; ni < 4; ++ni) {
          const int n = bn + wn + ni * 16 + l16;
          out[(size_t)m * ND + n] = (float)acc[mi][ni][r] * sc2;
        }
      }
    }
  }
}

// --------------------------------------------------------------------------

extern "C" void kernel_launch(void* const* d_in, const int* in_sizes, int n_in,
                              void* d_out, int out_size, void* d_ws, size_t ws_size,
                              hipStream_t stream) {
  const float* x = (const float*)d_in[0];
  const float* w = (const float*)d_in[1];
  const float* nw = (const float*)d_in[2];
  float* out = (float*)d_out;

  char* ws = (char*)d_ws;
  signed char* xq = (signed char*)ws;
  signed char* wq = (signed char*)(ws + ((size_t)1 << 24));
  float* gamma = (float*)(ws + ((size_t)2 << 24));
  float* part = (float*)(ws + ((size_t)2 << 24) + 16384);

  // co-residency-safe grid (pure query, capture-safe); grid-stride loops make
  // any grid size correct and every call does identical work.
  int blocks_per_cu = 0;
  (void)hipOccupancyMaxActiveBlocksPerMultiprocessor(
      &blocks_per_cu, (const void*)k_fused, 256, 0);
  if (blocks_per_cu < 1) blocks_per_cu = 1;
  int nblk = blocks_per_cu * 256;  // 256 CUs
  if (nblk > NTILE) nblk = NTILE;

  void* args[] = {(void*)&x,  (void*)&w,     (void*)&nw,   (void*)&xq,
                  (void*)&wq, (void*)&gamma, (void*)&part, (void*)&out};
  hipLaunchCooperativeKernel((const void*)k_fused, dim3(nblk), dim3(256), args,
                             0, stream);
}

// Round 5
// 244.244 us; speedup vs baseline: 1.8404x; 1.8404x over previous
//
#include <hip/hip_runtime.h>
#include <cstdint>
#include <cstddef>

// FusedBitLinear: RMSNorm -> ternary W quant (absmean) -> int8 activation quant
// -> int GEMM (MFMA i8) -> rescale by alpha*gamma[m]/127.
//
// M=4096 tokens, K=4096, N=4096. fp32 in/out.
//
// R4 lesson: never cap min-waves on the GEMM (launch_bounds(256,4) -> VGPR 64
// -> accumulator spill -> 4.6x regression). R5: 3 dispatches, wave-per-row
// side kernels (256B/lane MLP, shuffle-only reductions). Alpha path bit-exact
// vs R3 (reduction order + true division preserved); x-path uses reciprocal
// multiplies (x_q +-1 flips are worth ~4e-4 absmax, harmless).
//
// ws layout:
//   [0, 16M)            xq   int8 [4096][4096]
//   [16M, 32M)          wq   int8 [4096][4096]
//   [32M, +16KB)        gamma float[4096]
//   [+16KB, +32KB)      alpha partials float[4096]
//   [+32KB, +4B)        alpha float[1]

#define KD 4096
#define MD 4096
#define ND 4096

typedef int i32x4 __attribute__((ext_vector_type(4)));

__device__ __forceinline__ void gl2lds16(const signed char* g, signed char* l) {
  __builtin_amdgcn_global_load_lds(
      (const __attribute__((address_space(1))) void*)g,
      (__attribute__((address_space(3))) void*)l, 16, 0, 0);
}

__device__ __forceinline__ float wave_sum(float v) {
#pragma unroll
  for (int off = 32; off; off >>= 1) v += __shfl_down(v, off, 64);
  return v;
}
__device__ __forceinline__ float wave_max(float v) {
#pragma unroll
  for (int off = 32; off; off >>= 1) v = fmaxf(v, __shfl_down(v, off, 64));
  return v;
}

// ---------------- pass 1: per-row |W| partial sums (EXACT R3 code) --------

__global__ __launch_bounds__(256) void k_alpha_part(const float* __restrict__ w,
                                                    float* __restrict__ part) {
  __shared__ float red[4];
  const int tid = threadIdx.x;
  const float4* w4 = (const float4*)(w + (size_t)blockIdx.x * 4096);
  float s = 0.f;
#pragma unroll
  for (int i = 0; i < 4; ++i) {
    float4 v = w4[i * 256 + tid];
    s += fabsf(v.x) + fabsf(v.y) + fabsf(v.z) + fabsf(v.w);
  }
  s = wave_sum(s);
  if ((tid & 63) == 0) red[tid >> 6] = s;
  __syncthreads();
  if (tid == 0) part[blockIdx.x] = (red[0] + red[1]) + (red[2] + red[3]);
}

// ---------------- pass 2: fused quantization, wave-per-row ----------------
// blocks [0,1024): alpha via R3's exact 256-thread reduction (bit-identical,
//   deterministic), then each wave ternary-quants row bid*4+wave (true div).
//   Block 0 publishes alpha.
// blocks [1024,2048): each wave does RMSNorm+gamma+int8 quant of x row
//   (bid-1024)*4+wave. No barriers; 16 float4 in flight per lane.

__global__ __launch_bounds__(256) void k_quant_all(const float* __restrict__ w,
                                                   const float* __restrict__ x,
                                                   const float* __restrict__ nw,
                                                   const float* __restrict__ part,
                                                   signed char* __restrict__ wq,
                                                   signed char* __restrict__ xq,
                                                   float* __restrict__ gamma,
                                                   float* __restrict__ alpha_out) {
  const int tid = threadIdx.x;
  const int bid = blockIdx.x;
  const int lane = tid & 63;
  const int wave = tid >> 6;
  __shared__ float red[4];

  if (bid < 1024) {
    // ---- alpha: EXACT R3 reduction order ----
    float s = 0.f;
#pragma unroll
    for (int i = 0; i < 16; ++i) s += part[i * 256 + tid];
    s = wave_sum(s);
    if ((tid & 63) == 0) red[tid >> 6] = s;
    __syncthreads();
    const float alpha =
        fmaxf(((red[0] + red[1]) + (red[2] + red[3])) * (1.0f / 16777216.0f),
              1e-10f);
    if (bid == 0 && tid == 0) alpha_out[0] = alpha;

    // ---- wave-per-row W quant (true division: bit-identical w_q) ----
    const int row = bid * 4 + wave;
    const float4* w4 = (const float4*)(w + (size_t)row * 4096);
    uint32_t* wqi = (uint32_t*)(wq + (size_t)row * 4096);
#pragma unroll
    for (int j = 0; j < 16; ++j) {
      float4 v = w4[j * 64 + lane];
      int q0 = (int)fminf(fmaxf(rintf(v.x / alpha), -1.f), 1.f);
      int q1 = (int)fminf(fmaxf(rintf(v.y / alpha), -1.f), 1.f);
      int q2 = (int)fminf(fmaxf(rintf(v.z / alpha), -1.f), 1.f);
      int q3 = (int)fminf(fmaxf(rintf(v.w / alpha), -1.f), 1.f);
      wqi[j * 64 + lane] = (uint32_t)(q0 & 255) | ((uint32_t)(q1 & 255) << 8) |
                           ((uint32_t)(q2 & 255) << 16) |
                           ((uint32_t)(q3 & 255) << 24);
    }
  } else {
    // ---- wave-per-row RMSNorm + gamma + x quant ----
    const int row = (bid - 1024) * 4 + wave;
    const float4* x4 = (const float4*)(x + (size_t)row * 4096);
    const float4* n4 = (const float4*)nw;
    float4 xv[16];
    float ss = 0.f;
#pragma unroll
    for (int j = 0; j < 16; ++j) {
      xv[j] = x4[j * 64 + lane];
      ss += xv[j].x * xv[j].x + xv[j].y * xv[j].y + xv[j].z * xv[j].z +
            xv[j].w * xv[j].w;
    }
    ss = wave_sum(ss);
    ss = __shfl(ss, 0, 64);
    const float rms = sqrtf(ss * (1.0f / 4096.0f) + 1e-6f);
    const float inv_rms = 1.0f / rms;

    float mx = 0.f;
#pragma unroll
    for (int j = 0; j < 16; ++j) {
      float4 nv = n4[j * 64 + lane];
      float a0 = xv[j].x * inv_rms * nv.x;
      float a1 = xv[j].y * inv_rms * nv.y;
      float a2 = xv[j].z * inv_rms * nv.z;
      float a3 = xv[j].w * inv_rms * nv.w;
      mx = fmaxf(mx, fmaxf(fmaxf(fabsf(a0), fabsf(a1)),
                           fmaxf(fabsf(a2), fabsf(a3))));
    }
    mx = wave_max(mx);
    mx = __shfl(mx, 0, 64);
    const float g = fmaxf(mx, 1e-10f);
    if (lane == 0) gamma[row] = g;
    const float s127 = 127.0f / g;

    uint32_t* xqi = (uint32_t*)(xq + (size_t)row * 4096);
#pragma unroll
    for (int j = 0; j < 16; ++j) {
      float4 nv = n4[j * 64 + lane];
      float a0 = xv[j].x * inv_rms * nv.x;
      float a1 = xv[j].y * inv_rms * nv.y;
      float a2 = xv[j].z * inv_rms * nv.z;
      float a3 = xv[j].w * inv_rms * nv.w;
      int q0 = (int)fminf(fmaxf(rintf(a0 * s127), -128.f), 127.f);
      int q1 = (int)fminf(fmaxf(rintf(a1 * s127), -128.f), 127.f);
      int q2 = (int)fminf(fmaxf(rintf(a2 * s127), -128.f), 127.f);
      int q3 = (int)fminf(fmaxf(rintf(a3 * s127), -128.f), 127.f);
      xqi[j * 64 + lane] = (uint32_t)(q0 & 255) | ((uint32_t)(q1 & 255) << 8) |
                           ((uint32_t)(q2 & 255) << 16) |
                           ((uint32_t)(q3 & 255) << 24);
    }
  }
}

// ------------- int8 GEMM (EXACT R3 structure: 93us, MfmaUtil ~30) ---------
// 128x128 tile, BK=128 (32KB LDS), 4 waves 2x2, 4x4 MFMA 16x16x64 i8,
// swizzled global_load_lds staging, 0 bank conflicts measured.

__global__ __launch_bounds__(256) void k_gemm(const signed char* __restrict__ xq,
                                              const signed char* __restrict__ wq,
                                              const float* __restrict__ gamma,
                                              const float* __restrict__ alpha_p,
                                              float* __restrict__ out) {
  __shared__ __align__(16) signed char As[128 * 128];
  __shared__ __align__(16) signed char Bs[128 * 128];
  const int tid = threadIdx.x;
  const int lane = tid & 63;
  const int wave = tid >> 6;
  const int wm = (wave >> 1) * 64;
  const int wn = (wave & 1) * 64;
  const int quad = lane >> 4;
  const int l16 = lane & 15;
  const int bm = blockIdx.y * 128;
  const int bn = blockIdx.x * 128;

  const signed char* Ag = xq + (size_t)bm * KD;
  const signed char* Bg = wq + (size_t)bn * KD;

  const int lr = lane >> 3;
  const int sc = (lane & 7) ^ lr;
  const signed char* agp[4];
  const signed char* bgp[4];
  signed char* la[4];
  signed char* lb[4];
#pragma unroll
  for (int i = 0; i < 4; ++i) {
    const int R = i * 32 + wave * 8 + lr;
    agp[i] = Ag + (size_t)R * KD + sc * 16;
    bgp[i] = Bg + (size_t)R * KD + sc * 16;
    la[i] = &As[(i * 32 + wave * 8) * 128];
    lb[i] = &Bs[(i * 32 + wave * 8) * 128];
  }

  i32x4 acc[4][4];
#pragma unroll
  for (int i = 0; i < 4; ++i)
#pragma unroll
    for (int j = 0; j < 4; ++j) acc[i][j] = (i32x4){0, 0, 0, 0};

  const int swz = l16 & 7;

  for (int k0 = 0; k0 < KD; k0 += 128) {
    __syncthreads();
#pragma unroll
    for (int i = 0; i < 4; ++i) gl2lds16(agp[i] + k0, la[i]);
#pragma unroll
    for (int i = 0; i < 4; ++i) gl2lds16(bgp[i] + k0, lb[i]);
    __syncthreads();

#pragma unroll
    for (int ks = 0; ks < 2; ++ks) {
      const int pos = ((ks * 4 + quad) ^ swz) * 16;
      i32x4 af[4], bf[4];
#pragma unroll
      for (int mi = 0; mi < 4; ++mi)
        af[mi] = *(const i32x4*)&As[(wm + mi * 16 + l16) * 128 + pos];
#pragma unroll
      for (int ni = 0; ni < 4; ++ni)
        bf[ni] = *(const i32x4*)&Bs[(wn + ni * 16 + l16) * 128 + pos];
#pragma unroll
      for (int mi = 0; mi < 4; ++mi)
#pragma unroll
        for (int ni = 0; ni < 4; ++ni)
          acc[mi][ni] = __builtin_amdgcn_mfma_i32_16x16x64_i8(af[mi], bf[ni],
                                                              acc[mi][ni], 0, 0, 0);
    }
  }

  const float alpha = alpha_p[0];
#pragma unroll
  for (int mi = 0; mi < 4; ++mi) {
#pragma unroll
    for (int r = 0; r < 4; ++r) {
      const int m = bm + wm + mi * 16 + quad * 4 + r;
      const float s = (alpha * gamma[m]) / 127.0f;
#pragma unroll
      for (int ni = 0; ni < 4; ++ni) {
        const int n = bn + wn + ni * 16 + l16;
        out[(size_t)m * ND + n] = (float)acc[mi][ni][r] * s;
      }
    }
  }
}

// --------------------------------------------------------------------------

extern "C" void kernel_launch(void* const* d_in, const int* in_sizes, int n_in,
                              void* d_out, int out_size, void* d_ws, size_t ws_size,
                              hipStream_t stream) {
  const float* x = (const float*)d_in[0];
  const float* w = (const float*)d_in[1];
  const float* nw = (const float*)d_in[2];
  float* out = (float*)d_out;

  char* ws = (char*)d_ws;
  signed char* xq = (signed char*)ws;
  signed char* wq = (signed char*)(ws + ((size_t)1 << 24));
  float* gamma = (float*)(ws + ((size_t)2 << 24));
  float* part = (float*)(ws + ((size_t)2 << 24) + 16384);
  float* alpha = (float*)(ws + ((size_t)2 << 24) + 32768);

  k_alpha_part<<<4096, 256, 0, stream>>>(w, part);
  k_quant_all<<<2048, 256, 0, stream>>>(w, x, nw, part, wq, xq, gamma, alpha);
  dim3 g(ND / 128, MD / 128);
  k_gemm<<<g, 256, 0, stream>>>(xq, wq, gamma, alpha, out);
}